// Round 9
// baseline (189.447 us; speedup 1.0000x reference)
//
#include <hip/hip_runtime.h>

// LATTE forward, fully reduced:
//   R2: message = v[dst] => h_m = v; R6: beta-softmax over heads, edges/flags dead.
//   out = ReLU(LN(v * sm(v)) * gamma + beta),  v = feat@Wr + br,
//   sm[n,h] = softmax_h(lrelu(v_n.rl_h + v_n.rr_h)).
// Ledger: R9/R12 pass (40.4us fused, 1 block/CU, eff BW 1.9 TB/s). R15 pass
//   (512 blk, 2/CU, Occ 29%, eff 2.7 TB/s) but traffic x2 => 58us. R13/R14
//   tripwire <=> 16-deep DMA bursts. RULE: 8 DMA/thread per burst, R12 phase
//   skeleton (stage -> A-loads -> barrier -> MFMA -> barrier), fenced epilogue.
// R16/R17: co-residency WITHOUT the traffic bill:
//   - nontemporal feat loads + out stores: no L2 allocation => Wt (128KB) stays
//     perma-hot in every XCD L2 => B-DMA ~free regardless of block count.
//   - 782 blocks x 256 thr (4 waves), 1 tile/wave (3128 slots >= 3125 tiles).
//   - B staged in four 32KB K-quarters (8 slots/thread each = proven depth);
//     XOR swizzle per quarter: phys p = logical l ^ (n&7) (2-way max on read).
//   - 32KB LDS (B-quarter aliased by 4x8KB epilogue scratch), ~128 VGPR,
//     __launch_bounds__(256,4) => 3-4 blocks/CU.
// R18: R16 with compile fix only — __builtin_nontemporal_* requires clang
//   ext-vector types, not HIP_vector_type float4; use f32x4 at the 3 sites.

#define NN 50000
#define NT 3125    // 50000/16 row-tiles
#define NBLK 782   // 782*4 = 3128 wave-slots >= 3125
#define NEG 0.2f
#define EPSV 1e-5f

typedef __attribute__((ext_vector_type(8))) short bf16x8;
typedef __attribute__((ext_vector_type(4))) float f32x4;

#define LDS_FENCE() asm volatile("s_waitcnt lgkmcnt(0)" ::: "memory")

__device__ __forceinline__ short f2bf(float f) {   // RNE fp32->bf16
    unsigned u = __float_as_uint(f);
    u += 0x7fff + ((u >> 16) & 1);
    return (short)(u >> 16);
}

__device__ __forceinline__ void ld_g2l_16(void* lds, const void* g) {
    __builtin_amdgcn_global_load_lds(
        (const __attribute__((address_space(1))) unsigned int*)g,
        (__attribute__((address_space(3))) unsigned int*)lds, 16, 0, 0);
}

// 8 blocks: Wt[n][k] = bf16(Wr[k][n]) via LDS (coalesced reads, 64B/thread writes).
// UNCHANGED from the proven R12 version. Normal (caching) stores: Wt wants L2/L3.
__global__ __launch_bounds__(256) void prep_kernel(
    const float* __restrict__ Wr, unsigned short* __restrict__ Wt)
{
    __shared__ float ws[32 * 256];   // 32 KB
    int t = threadIdx.x;
    int kb = blockIdx.x * 32;
#pragma unroll
    for (int i = 0; i < 32; ++i)
        ws[i * 256 + t] = Wr[(size_t)(kb + i) * 256 + t];
    __syncthreads();
#pragma unroll
    for (int c = 0; c < 4; ++c) {
        bf16x8 o;
#pragma unroll
        for (int j = 0; j < 8; ++j)
            o[j] = f2bf(ws[(c * 8 + j) * 256 + t]);
        *reinterpret_cast<bf16x8*>(&Wt[(size_t)t * 256 + kb + c * 8]) = o;
    }
}

// Per-tile epilogue on the MFMA C-layout (row=quad*4+r, col=ct*16+cl). Uses the wave's
// private 8KB LDS scratch tb for the coalesced store-transpose. R12-verbatim except
// the final stores are nontemporal (out is write-once, keep it out of L2).
__device__ __forceinline__ void epilogue(
    f32x4* acc, int row0, int lane, int cl, int quad,
    const float* __restrict__ br, const float* __restrict__ rl,
    const float* __restrict__ rr, const float* __restrict__ gamma,
    const float* __restrict__ beta, float* tb, float* __restrict__ out)
{
#pragma unroll
    for (int ct = 0; ct < 16; ++ct) {
        float bc = br[ct * 16 + cl];
#pragma unroll
        for (int r = 0; r < 4; ++r) acc[ct][r] += bc;
    }
    float z[4][4];
#pragma unroll
    for (int h = 0; h < 4; ++h) {
        float sl[4] = {0, 0, 0, 0}, sr[4] = {0, 0, 0, 0};
#pragma unroll
        for (int j = 0; j < 4; ++j) {
            int ct = h * 4 + j;
            float rlc = rl[ct * 16 + cl], rrc = rr[ct * 16 + cl];
#pragma unroll
            for (int r = 0; r < 4; ++r) {
                sl[r] += acc[ct][r] * rlc;
                sr[r] += acc[ct][r] * rrc;
            }
        }
#pragma unroll
        for (int off = 1; off < 16; off <<= 1)
#pragma unroll
            for (int r = 0; r < 4; ++r) {
                sl[r] += __shfl_xor(sl[r], off, 64);
                sr[r] += __shfl_xor(sr[r], off, 64);
            }
#pragma unroll
        for (int r = 0; r < 4; ++r) {
            float x = sl[r] + sr[r];
            z[h][r] = x > 0.f ? x : NEG * x;
        }
    }
    float gg[4][4];
#pragma unroll
    for (int r = 0; r < 4; ++r) {
        float mx = fmaxf(fmaxf(z[0][r], z[1][r]), fmaxf(z[2][r], z[3][r]));
        float e0 = __expf(z[0][r] - mx), e1 = __expf(z[1][r] - mx);
        float e2 = __expf(z[2][r] - mx), e3 = __expf(z[3][r] - mx);
        float inv = 1.f / (e0 + e1 + e2 + e3);
        gg[0][r] = e0 * inv; gg[1][r] = e1 * inv;
        gg[2][r] = e2 * inv; gg[3][r] = e3 * inv;
    }
    float s[4] = {0, 0, 0, 0}, s2[4] = {0, 0, 0, 0};
#pragma unroll
    for (int ct = 0; ct < 16; ++ct) {
        int h = ct >> 2;
#pragma unroll
        for (int r = 0; r < 4; ++r) {
            float o = acc[ct][r] * gg[h][r];
            acc[ct][r] = o;
            s[r] += o;
            s2[r] += o * o;
        }
    }
#pragma unroll
    for (int off = 1; off < 16; off <<= 1)
#pragma unroll
        for (int r = 0; r < 4; ++r) {
            s[r] += __shfl_xor(s[r], off, 64);
            s2[r] += __shfl_xor(s2[r], off, 64);
        }
    float mu[4], rstd[4];
#pragma unroll
    for (int r = 0; r < 4; ++r) {
        mu[r] = s[r] * (1.f / 256.f);
        float var = s2[r] * (1.f / 256.f) - mu[r] * mu[r];
        rstd[r] = rsqrtf(var + EPSV);
    }
#pragma unroll
    for (int p = 0; p < 2; ++p) {
#pragma unroll
        for (int ct = 0; ct < 16; ++ct) {
            float ga = gamma[ct * 16 + cl], be = beta[ct * 16 + cl];
            float v0 = fmaxf((acc[ct][2 * p + 0] - mu[2 * p + 0]) * rstd[2 * p + 0] * ga + be, 0.f);
            float v1 = fmaxf((acc[ct][2 * p + 1] - mu[2 * p + 1]) * rstd[2 * p + 1] * ga + be, 0.f);
            tb[(quad * 2 + 0) * 256 + ct * 16 + cl] = v0;
            tb[(quad * 2 + 1) * 256 + ct * 16 + cl] = v1;
        }
        LDS_FENCE();   // same-wave cross-lane RAW on LDS
#pragma unroll
        for (int sl8 = 0; sl8 < 8; ++sl8) {
            int trow = (sl8 >> 1) * 4 + 2 * p + (sl8 & 1);
            f32x4 v4 = *reinterpret_cast<const f32x4*>(&tb[sl8 * 256 + lane * 4]);
            __builtin_nontemporal_store(
                v4, reinterpret_cast<f32x4*>(&out[(size_t)(row0 + trow) * 256 + lane * 4]));
        }
        LDS_FENCE();   // WAR before next pass / next tile overwrites
    }
}

// 256 threads = 4 waves; wave-slot ws = blockIdx*4+wave owns tile ws (ws<3125).
// Idle slots (3) stage + barrier with row0=0 loads, skip MFMA/epilogue (wave-uniform).
// Per K-quarter q: stage 32KB of B (slot s: n=s>>3, phys p=s&7, logical l=p^(n&7)),
// load A-quarter (nontemporal), barrier, 32 MFMAs. After 4 quarters + barrier the
// LDS becomes 4x8KB per-wave epilogue scratch (alias, R12-proven pattern).
// mfma 16x16x32 bf16: A[m=lane&15][k=quad*8+j], B[k][n=lane&15], C row=quad*4+r col=ct*16+cl.
__global__ __launch_bounds__(256, 4) void fused_kernel(
    const float* __restrict__ feat, const unsigned short* __restrict__ Wt,
    const float* __restrict__ br, const float* __restrict__ rl,
    const float* __restrict__ rr, const float* __restrict__ gamma,
    const float* __restrict__ beta, float* __restrict__ out)
{
    __shared__ __align__(16) char smem[32768];   // B-quarter, then 4x8KB scratch
    unsigned short* Bq = (unsigned short*)smem;
    const int t = threadIdx.x;
    const int wave = t >> 6, lane = t & 63;
    const int cl = lane & 15, quad = lane >> 4;
    const int ws = blockIdx.x * 4 + wave;        // [0, 3128)
    const bool has = ws < NT;
    const int r0 = (has ? ws : 0) * 16;

    f32x4 acc0[16];
#pragma unroll
    for (int i = 0; i < 16; ++i)
        acc0[i] = (f32x4){0.f, 0.f, 0.f, 0.f};
    const float* arow0 = feat + (size_t)(r0 + cl) * 256;

#pragma unroll
    for (int q = 0; q < 4; ++q) {
        if (q) __syncthreads();        // protect LDS before overwrite
#pragma unroll
        for (int c = 0; c < 8; ++c) {  // stage 32KB B-quarter: 8 slots/thread (proven depth)
            int s = c * 256 + t;
            int n = s >> 3;
            int l = (s & 7) ^ (n & 7);
            ld_g2l_16(&Bq[(size_t)(c * 256 + wave * 64) * 8],
                      Wt + n * 256 + q * 64 + l * 8);
        }
        // A fragments for this K-quarter (nontemporal: feat must not evict Wt from L2)
        bf16x8 af0[2];
#pragma unroll
        for (int kk = 0; kk < 2; ++kk) {
            int k0 = q * 64 + kk * 32 + quad * 8;
            f32x4 a0 = __builtin_nontemporal_load(
                reinterpret_cast<const f32x4*>(arow0 + k0));
            f32x4 a1 = __builtin_nontemporal_load(
                reinterpret_cast<const f32x4*>(arow0 + k0 + 4));
            af0[kk][0] = f2bf(a0[0]); af0[kk][1] = f2bf(a0[1]);
            af0[kk][2] = f2bf(a0[2]); af0[kk][3] = f2bf(a0[3]);
            af0[kk][4] = f2bf(a1[0]); af0[kk][5] = f2bf(a1[1]);
            af0[kk][6] = f2bf(a1[2]); af0[kk][7] = f2bf(a1[3]);
        }
        __syncthreads();               // drains vmcnt for the DMA
        if (has) {                     // wave-uniform; no barrier inside
#pragma unroll
            for (int kk = 0; kk < 2; ++kk) {
                int ksl = kk * 4 + quad;
#pragma unroll
                for (int ct = 0; ct < 16; ++ct) {
                    int n = ct * 16 + cl;
                    bf16x8 bf = *reinterpret_cast<const bf16x8*>(
                        &Bq[(size_t)(n * 8 + (ksl ^ (n & 7))) * 8]);
                    acc0[ct] = __builtin_amdgcn_mfma_f32_16x16x32_bf16(af0[kk], bf, acc0[ct], 0, 0, 0);
                }
            }
        }
    }
    __syncthreads();   // all waves done reading Bq; LDS becomes per-wave scratch

    float* tb = reinterpret_cast<float*>(smem) + wave * 2048;
    if (has)
        epilogue(acc0, r0, lane, cl, quad, br, rl, rr, gamma, beta, tb, out);
}

extern "C" void kernel_launch(void* const* d_in, const int* in_sizes, int n_in,
                              void* d_out, int out_size, void* d_ws, size_t ws_size,
                              hipStream_t stream) {
    const float* feat = (const float*)d_in[0];
    const float* Wr   = (const float*)d_in[3];
    const float* br   = (const float*)d_in[4];
    const float* rl   = (const float*)d_in[7];
    const float* rr   = (const float*)d_in[8];
    const float* gam  = (const float*)d_in[9];
    const float* bet  = (const float*)d_in[10];
    float* out = (float*)d_out;
    unsigned short* Wt = (unsigned short*)d_ws;   // 128 KB bf16 W^T

    prep_kernel<<<8, 256, 0, stream>>>(Wr, Wt);
    fused_kernel<<<NBLK, 256, 0, stream>>>(feat, Wt, br, rl, rr, gam, bet, out);
}

// Round 10
// 153.345 us; speedup vs baseline: 1.2354x; 1.2354x over previous
//
#include <hip/hip_runtime.h>

// LATTE forward, fully reduced:
//   R2: message = v[dst] => h_m = v; R6: beta-softmax over heads, edges/flags dead.
//   out = ReLU(LN(v * sm(v)) * gamma + beta),  v = feat@Wr + br,
//   sm[n,h] = softmax_h(lrelu(v_n.rl_h + v_n.rr_h)).
// Ledger: R12 anchor (153.1us total, fused 40.4us, hbm 78MB, WRITE exactly 50MB,
//   256blk x 512thr, 4 barriers). R15/R18 (>256-block grids): WRITE doubled to
//   ~99MB regardless of store flavor, fused 58/70us => co-residency branch
//   abandoned. R13/R14 tripwire <=> 16-deep DMA bursts. nt loads killed L3 reuse
//   (FETCH 26->51MB). RULES: grid 256x512; <=8 DMA in flight per thread; <=24
//   outstanding vmem; fenced scratch epilogue; normal loads/stores.
// R19: R12 with the two K-half phases FUSED: full B (128KB) staged once via two
//   8-deep DMA bursts separated by s_waitcnt vmcnt(16) (retires the 8 older DMAs;
//   A0's 16 loads are the newer 16 => DMA depth <=8 always). 2 barriers total.
//   A half-1 loaded RAW into regs right after the stage barrier, before the half-0
//   MFMA loop (HBM latency hides under 256 MFMAs), converted after. B-swizzle =
//   R13's verified 32-slot bijection. Scratch epilogue aliases Bs after barrier.

#define NN 50000
#define NT 3125    // 50000/16 row-tiles
#define NWS 2048   // wave-slots = 256 blocks x 8 waves
#define NBLK 256
#define NEG 0.2f
#define EPSV 1e-5f

typedef __attribute__((ext_vector_type(8))) short bf16x8;
typedef __attribute__((ext_vector_type(4))) float f32x4;

#define LDS_FENCE() asm volatile("s_waitcnt lgkmcnt(0)" ::: "memory")

__device__ __forceinline__ short f2bf(float f) {   // RNE fp32->bf16
    unsigned u = __float_as_uint(f);
    u += 0x7fff + ((u >> 16) & 1);
    return (short)(u >> 16);
}

__device__ __forceinline__ void ld_g2l_16(void* lds, const void* g) {
    __builtin_amdgcn_global_load_lds(
        (const __attribute__((address_space(1))) unsigned int*)g,
        (__attribute__((address_space(3))) unsigned int*)lds, 16, 0, 0);
}

// 8 blocks: Wt[n][k] = bf16(Wr[k][n]) via LDS (coalesced reads, 64B/thread writes).
// UNCHANGED from the proven R12 version.
__global__ __launch_bounds__(256) void prep_kernel(
    const float* __restrict__ Wr, unsigned short* __restrict__ Wt)
{
    __shared__ float ws[32 * 256];   // 32 KB
    int t = threadIdx.x;
    int kb = blockIdx.x * 32;
#pragma unroll
    for (int i = 0; i < 32; ++i)
        ws[i * 256 + t] = Wr[(size_t)(kb + i) * 256 + t];
    __syncthreads();
#pragma unroll
    for (int c = 0; c < 4; ++c) {
        bf16x8 o;
#pragma unroll
        for (int j = 0; j < 8; ++j)
            o[j] = f2bf(ws[(c * 8 + j) * 256 + t]);
        *reinterpret_cast<bf16x8*>(&Wt[(size_t)t * 256 + kb + c * 8]) = o;
    }
}

// Per-tile epilogue on the MFMA C-layout (row=quad*4+r, col=ct*16+cl). Uses the wave's
// private 8KB LDS scratch tb for the coalesced store-transpose. R12-VERBATIM.
__device__ __forceinline__ void epilogue(
    f32x4* acc, int row0, int lane, int cl, int quad,
    const float* __restrict__ br, const float* __restrict__ rl,
    const float* __restrict__ rr, const float* __restrict__ gamma,
    const float* __restrict__ beta, float* tb, float* __restrict__ out)
{
#pragma unroll
    for (int ct = 0; ct < 16; ++ct) {
        float bc = br[ct * 16 + cl];
#pragma unroll
        for (int r = 0; r < 4; ++r) acc[ct][r] += bc;
    }
    float z[4][4];
#pragma unroll
    for (int h = 0; h < 4; ++h) {
        float sl[4] = {0, 0, 0, 0}, sr[4] = {0, 0, 0, 0};
#pragma unroll
        for (int j = 0; j < 4; ++j) {
            int ct = h * 4 + j;
            float rlc = rl[ct * 16 + cl], rrc = rr[ct * 16 + cl];
#pragma unroll
            for (int r = 0; r < 4; ++r) {
                sl[r] += acc[ct][r] * rlc;
                sr[r] += acc[ct][r] * rrc;
            }
        }
#pragma unroll
        for (int off = 1; off < 16; off <<= 1)
#pragma unroll
            for (int r = 0; r < 4; ++r) {
                sl[r] += __shfl_xor(sl[r], off, 64);
                sr[r] += __shfl_xor(sr[r], off, 64);
            }
#pragma unroll
        for (int r = 0; r < 4; ++r) {
            float x = sl[r] + sr[r];
            z[h][r] = x > 0.f ? x : NEG * x;
        }
    }
    float gg[4][4];
#pragma unroll
    for (int r = 0; r < 4; ++r) {
        float mx = fmaxf(fmaxf(z[0][r], z[1][r]), fmaxf(z[2][r], z[3][r]));
        float e0 = __expf(z[0][r] - mx), e1 = __expf(z[1][r] - mx);
        float e2 = __expf(z[2][r] - mx), e3 = __expf(z[3][r] - mx);
        float inv = 1.f / (e0 + e1 + e2 + e3);
        gg[0][r] = e0 * inv; gg[1][r] = e1 * inv;
        gg[2][r] = e2 * inv; gg[3][r] = e3 * inv;
    }
    float s[4] = {0, 0, 0, 0}, s2[4] = {0, 0, 0, 0};
#pragma unroll
    for (int ct = 0; ct < 16; ++ct) {
        int h = ct >> 2;
#pragma unroll
        for (int r = 0; r < 4; ++r) {
            float o = acc[ct][r] * gg[h][r];
            acc[ct][r] = o;
            s[r] += o;
            s2[r] += o * o;
        }
    }
#pragma unroll
    for (int off = 1; off < 16; off <<= 1)
#pragma unroll
        for (int r = 0; r < 4; ++r) {
            s[r] += __shfl_xor(s[r], off, 64);
            s2[r] += __shfl_xor(s2[r], off, 64);
        }
    float mu[4], rstd[4];
#pragma unroll
    for (int r = 0; r < 4; ++r) {
        mu[r] = s[r] * (1.f / 256.f);
        float var = s2[r] * (1.f / 256.f) - mu[r] * mu[r];
        rstd[r] = rsqrtf(var + EPSV);
    }
#pragma unroll
    for (int p = 0; p < 2; ++p) {
#pragma unroll
        for (int ct = 0; ct < 16; ++ct) {
            float ga = gamma[ct * 16 + cl], be = beta[ct * 16 + cl];
            float v0 = fmaxf((acc[ct][2 * p + 0] - mu[2 * p + 0]) * rstd[2 * p + 0] * ga + be, 0.f);
            float v1 = fmaxf((acc[ct][2 * p + 1] - mu[2 * p + 1]) * rstd[2 * p + 1] * ga + be, 0.f);
            tb[(quad * 2 + 0) * 256 + ct * 16 + cl] = v0;
            tb[(quad * 2 + 1) * 256 + ct * 16 + cl] = v1;
        }
        LDS_FENCE();   // same-wave cross-lane RAW on LDS
#pragma unroll
        for (int sl8 = 0; sl8 < 8; ++sl8) {
            int trow = (sl8 >> 1) * 4 + 2 * p + (sl8 & 1);
            float4 v4 = *reinterpret_cast<const float4*>(&tb[sl8 * 256 + lane * 4]);
            *reinterpret_cast<float4*>(&out[(size_t)(row0 + trow) * 256 + lane * 4]) = v4;
        }
        LDS_FENCE();   // WAR before next pass / next tile overwrites
    }
}

// 512 threads = 8 waves; wave-slot ws covers tiles [lo,hi), lo=(ws*3125)>>11 —
// 1 or 2 ADJACENT tiles (R12 partition). Both acc sets always computed (B shared);
// single-tile waves re-read tile0's A rows (L1 hit) and skip the second epilogue.
// LDS: FULL B, 8192 slots of 16B: slot s -> n=s>>5, kphys=s&31, klog=kphys^(n&31)
// (R13's verified bijection). Read: ks=kk*4+quad in [0,32), phys=(ks^(n&31)).
// mfma 16x16x32 bf16: A[m=lane&15][k=quad*8+j], B[k][n=lane&15], C row=quad*4+r col=ct*16+cl.
__global__ __launch_bounds__(512, 2) void fused_kernel(
    const float* __restrict__ feat, const unsigned short* __restrict__ Wt,
    const float* __restrict__ br, const float* __restrict__ rl,
    const float* __restrict__ rr, const float* __restrict__ gamma,
    const float* __restrict__ beta, float* __restrict__ out)
{
    __shared__ __align__(16) char smem[131072];   // 128KB full B; scratch aliases later
    unsigned short* Bs = (unsigned short*)smem;
    const int t = threadIdx.x;
    const int wave = t >> 6, lane = t & 63;
    const int cl = lane & 15, quad = lane >> 4;
    const int ws = blockIdx.x * 8 + wave;   // [0, 2048)
    const int lo = (ws * NT) >> 11;
    const int hi = ((ws + 1) * NT) >> 11;
    const bool act1 = (hi - lo) > 1;
    const int r0 = lo * 16;
    const int r1 = (act1 ? lo + 1 : lo) * 16;

    f32x4 acc0[16], acc1[16];
#pragma unroll
    for (int i = 0; i < 16; ++i) {
        acc0[i] = (f32x4){0.f, 0.f, 0.f, 0.f};
        acc1[i] = (f32x4){0.f, 0.f, 0.f, 0.f};
    }
    const float* arow0 = feat + (size_t)(r0 + cl) * 256;
    const float* arow1 = feat + (size_t)(r1 + cl) * 256;

    // ---- single memory phase ----
    // DMA burst 1: B rows n=0..127 (slots 0..4095), 8 slots/thread (proven depth)
#pragma unroll
    for (int c = 0; c < 8; ++c) {
        int s = c * 512 + t;
        int n = s >> 5;
        int klog = (s & 31) ^ (n & 31);
        ld_g2l_16(&Bs[(size_t)(c * 512 + wave * 64) * 8],
                  Wt + n * 256 + klog * 8);
    }
    // A fragments, K-half 0, both tiles: 16 float4 loads (R12's proven per-phase count)
    bf16x8 af0[4], af1[4];
#pragma unroll
    for (int kk = 0; kk < 4; ++kk) {
        int k0 = kk * 32 + quad * 8;
        f32x4 a0 = *reinterpret_cast<const f32x4*>(arow0 + k0);
        f32x4 a1 = *reinterpret_cast<const f32x4*>(arow0 + k0 + 4);
        f32x4 b0 = *reinterpret_cast<const f32x4*>(arow1 + k0);
        f32x4 b1 = *reinterpret_cast<const f32x4*>(arow1 + k0 + 4);
        af0[kk][0] = f2bf(a0[0]); af0[kk][1] = f2bf(a0[1]);
        af0[kk][2] = f2bf(a0[2]); af0[kk][3] = f2bf(a0[3]);
        af0[kk][4] = f2bf(a1[0]); af0[kk][5] = f2bf(a1[1]);
        af0[kk][6] = f2bf(a1[2]); af0[kk][7] = f2bf(a1[3]);
        af1[kk][0] = f2bf(b0[0]); af1[kk][1] = f2bf(b0[1]);
        af1[kk][2] = f2bf(b0[2]); af1[kk][3] = f2bf(b0[3]);
        af1[kk][4] = f2bf(b1[0]); af1[kk][5] = f2bf(b1[1]);
        af1[kk][6] = f2bf(b1[2]); af1[kk][7] = f2bf(b1[3]);
    }
    // Retire burst-1 DMAs before issuing burst 2 (the 16 A-loads are the newer 16;
    // waiting to <=16 outstanding drains the 8 older DMAs => DMA depth <=8 always).
    asm volatile("s_waitcnt vmcnt(16)" ::: "memory");
    // DMA burst 2: B rows n=128..255 (slots 4096..8191)
#pragma unroll
    for (int c = 8; c < 16; ++c) {
        int s = c * 512 + t;
        int n = s >> 5;
        int klog = (s & 31) ^ (n & 31);
        ld_g2l_16(&Bs[(size_t)(c * 512 + wave * 64) * 8],
                  Wt + n * 256 + klog * 8);
    }
    __syncthreads();   // drains vmcnt: full B resident, A0 converted

    // ---- single compute phase (no barriers inside) ----
    // Issue A K-half-1 RAW loads now: their HBM latency hides under mfma half-0.
    f32x4 raw[16];
#pragma unroll
    for (int kk = 0; kk < 4; ++kk) {
        int k0 = 128 + kk * 32 + quad * 8;
        raw[kk * 4 + 0] = *reinterpret_cast<const f32x4*>(arow0 + k0);
        raw[kk * 4 + 1] = *reinterpret_cast<const f32x4*>(arow0 + k0 + 4);
        raw[kk * 4 + 2] = *reinterpret_cast<const f32x4*>(arow1 + k0);
        raw[kk * 4 + 3] = *reinterpret_cast<const f32x4*>(arow1 + k0 + 4);
    }
    // mfma K-half 0 (ks = kk*4+quad in [0,16))
#pragma unroll
    for (int kk = 0; kk < 4; ++kk) {
        int ks = kk * 4 + quad;
#pragma unroll
        for (int ct = 0; ct < 16; ++ct) {
            int n = ct * 16 + cl;
            bf16x8 bf = *reinterpret_cast<const bf16x8*>(
                &Bs[(size_t)(n * 32 + (ks ^ (n & 31))) * 8]);
            acc0[ct] = __builtin_amdgcn_mfma_f32_16x16x32_bf16(af0[kk], bf, acc0[ct], 0, 0, 0);
            acc1[ct] = __builtin_amdgcn_mfma_f32_16x16x32_bf16(af1[kk], bf, acc1[ct], 0, 0, 0);
        }
    }
    // convert A K-half 1 (loads have landed under the MFMAs)
#pragma unroll
    for (int kk = 0; kk < 4; ++kk) {
        f32x4 a0 = raw[kk * 4 + 0], a1 = raw[kk * 4 + 1];
        f32x4 b0 = raw[kk * 4 + 2], b1 = raw[kk * 4 + 3];
        af0[kk][0] = f2bf(a0[0]); af0[kk][1] = f2bf(a0[1]);
        af0[kk][2] = f2bf(a0[2]); af0[kk][3] = f2bf(a0[3]);
        af0[kk][4] = f2bf(a1[0]); af0[kk][5] = f2bf(a1[1]);
        af0[kk][6] = f2bf(a1[2]); af0[kk][7] = f2bf(a1[3]);
        af1[kk][0] = f2bf(b0[0]); af1[kk][1] = f2bf(b0[1]);
        af1[kk][2] = f2bf(b0[2]); af1[kk][3] = f2bf(b0[3]);
        af1[kk][4] = f2bf(b1[0]); af1[kk][5] = f2bf(b1[1]);
        af1[kk][6] = f2bf(b1[2]); af1[kk][7] = f2bf(b1[3]);
    }
    // mfma K-half 1 (ks in [16,32))
#pragma unroll
    for (int kk = 0; kk < 4; ++kk) {
        int ks = 16 + kk * 4 + quad;
#pragma unroll
        for (int ct = 0; ct < 16; ++ct) {
            int n = ct * 16 + cl;
            bf16x8 bf = *reinterpret_cast<const bf16x8*>(
                &Bs[(size_t)(n * 32 + (ks ^ (n & 31))) * 8]);
            acc0[ct] = __builtin_amdgcn_mfma_f32_16x16x32_bf16(af0[kk], bf, acc0[ct], 0, 0, 0);
            acc1[ct] = __builtin_amdgcn_mfma_f32_16x16x32_bf16(af1[kk], bf, acc1[ct], 0, 0, 0);
        }
    }
    __syncthreads();   // all waves done reading Bs; LDS becomes per-wave scratch

    float* tb = reinterpret_cast<float*>(smem) + wave * 2048;
    epilogue(acc0, r0, lane, cl, quad, br, rl, rr, gamma, beta, tb, out);
    if (act1)
        epilogue(acc1, r1, lane, cl, quad, br, rl, rr, gamma, beta, tb, out);
}

extern "C" void kernel_launch(void* const* d_in, const int* in_sizes, int n_in,
                              void* d_out, int out_size, void* d_ws, size_t ws_size,
                              hipStream_t stream) {
    const float* feat = (const float*)d_in[0];
    const float* Wr   = (const float*)d_in[3];
    const float* br   = (const float*)d_in[4];
    const float* rl   = (const float*)d_in[7];
    const float* rr   = (const float*)d_in[8];
    const float* gam  = (const float*)d_in[9];
    const float* bet  = (const float*)d_in[10];
    float* out = (float*)d_out;
    unsigned short* Wt = (unsigned short*)d_ws;   // 128 KB bf16 W^T

    prep_kernel<<<8, 256, 0, stream>>>(Wr, Wt);
    fused_kernel<<<NBLK, 512, 0, stream>>>(feat, Wt, br, rl, rr, gam, bet, out);
}